// Round 9
// baseline (8824.067 us; speedup 1.0000x reference)
//
#include <hip/hip_runtime.h>

typedef __attribute__((ext_vector_type(8))) _Float16 half8;
typedef __attribute__((ext_vector_type(4))) float f32x4;

#define HH 64
#define TT 12
#define TOUT 12
#define CC 10
#define BNTOT 131072

__device__ __forceinline__ float sigm(float x){
  return __builtin_amdgcn_rcpf(1.0f + __expf(-x));
}
__device__ __forceinline__ float tanh_f(float x){
  return 1.0f - 2.0f * __builtin_amdgcn_rcpf(1.0f + __expf(2.0f * x));
}

struct W {
  const float* ewih; const float* ewhh; const float* ebih; const float* ebhh;
  const float* dwih; const float* dwhh; const float* dbih; const float* dbhh;
  const float* l1w;  const float* l1b;  const float* l2w;  const float* l2b;
  const float* emb;
};

#define MFMAH(A,B,C) __builtin_amdgcn_mfma_f32_16x16x32_f16((A),(B),(C),0,0,0)

// group a (0..11) -> w_hh row base: a0-3 pre_r, a4-7 pre_z, a8-11 gh_n
__device__ __forceinline__ int rowbase(int a){
  return (a < 4) ? a*16 : (a < 8) ? 64 + (a - 4)*16 : 128 + (a - 8)*16;
}

// One GRU step. aug path fp32 VALU (exact); h-part single fp16 MFMA per (a,kt).
// All per-step operands come from LDS (24 KB shared tiles) or registers.
__device__ __forceinline__ void run_step(
    const float x0[4], const float x1[4],
    const _Float16* __restrict__ tiles,
    const float aw0[8], const float aw1[8], const float ab[8],
    const float ghb[4], const float gxw0[4], const float gxw1[4], const float gxb[4],
    float hc[16], half8 ahi[2], float* hb,
    int c15, int quad, int lane8)
{
  f32x4 acc[12];
  #pragma unroll
  for (int a = 0; a < 8; ++a){
    #pragma unroll
    for (int r = 0; r < 4; ++r)
      acc[a][r] = fmaf(x0[r], aw0[a], fmaf(x1[r], aw1[a], ab[a]));
  }
  #pragma unroll
  for (int q = 0; q < 4; ++q){
    #pragma unroll
    for (int r = 0; r < 4; ++r) acc[8 + q][r] = ghb[q];
  }
  #pragma unroll
  for (int a = 0; a < 12; ++a){
    #pragma unroll
    for (int kt = 0; kt < 2; ++kt){
      const half8 bh = *(const half8*)(tiles + (a*2 + kt)*512 + lane8);
      acc[a] = MFMAH(ahi[kt], bh, acc[a]);
    }
  }
  // gates (gx_n inline fp32) + transpose via hb (stride 68, 16B-aligned rows)
  #pragma unroll
  for (int q = 0; q < 4; ++q){
    #pragma unroll
    for (int r = 0; r < 4; ++r){
      const float pr = acc[q][r], pz = acc[4 + q][r], gh = acc[8 + q][r];
      const float gx = fmaf(x0[r], gxw0[q], fmaf(x1[r], gxw1[q], gxb[q]));
      const float rr = sigm(pr), zz = sigm(pz);
      const float nn = tanh_f(fmaf(rr, gh, gx));
      const float hn = (1.0f - zz)*nn + zz*hc[q*4 + r];
      hc[q*4 + r] = hn;
      hb[(quad*4 + r)*68 + q*16 + c15] = hn;
    }
  }
  const int m = c15, q8 = quad*8;
  #pragma unroll
  for (int kt = 0; kt < 2; ++kt){
    const f32x4* p = (const f32x4*)&hb[m*68 + kt*32 + q8];
    f32x4 a = p[0], b = p[1];
    half8 h;
    h[0]=(_Float16)a[0]; h[1]=(_Float16)a[1]; h[2]=(_Float16)a[2]; h[3]=(_Float16)a[3];
    h[4]=(_Float16)b[0]; h[5]=(_Float16)b[1]; h[6]=(_Float16)b[2]; h[7]=(_Float16)b[3];
    ahi[kt] = h;
  }
}

__global__ __launch_bounds__(256, 3) void rnn_mfma5(
    const float* __restrict__ X, W wp, float* __restrict__ out)
{
  __shared__ __align__(16) _Float16 tiles_s[26*512];   // 24 whh tiles + 2 hv/v
  __shared__ __align__(16) float wbuf_s[4*1712];       // per-wave hb/hv/va/lvb

  const int tid = threadIdx.x;
  const int wid = tid >> 6, lane = tid & 63;
  const int quad = lane >> 4, c15 = lane & 15;
  const int lane8 = lane*8;
  float* wl  = wbuf_s + wid*1712;
  float* hb  = wl;                 // 16*68
  float* hv  = wl + 1088;          // 16*26 (stride 26: fits 3 blocks/CU)
  float* va  = wl + 1504;          // 16*12
  float* lvb = wl + 1696;          // 16
  const int wavebase = (blockIdx.x*4 + wid)*16;

  // ---- X row -> regs: lane holds sample m=c15, elements [quad*8, quad*8+8) ----
  float xr[8];
  if (quad < 3){
    const float* xp = X + (size_t)(wavebase + c15)*24 + quad*8;
    f32x4 p0 = *(const f32x4*)xp, p1 = *(const f32x4*)(xp + 4);
    xr[0]=p0[0]; xr[1]=p0[1]; xr[2]=p0[2]; xr[3]=p0[3];
    xr[4]=p1[0]; xr[5]=p1[1]; xr[6]=p1[2]; xr[7]=p1[3];
  } else {
    #pragma unroll
    for (int i = 0; i < 8; ++i) xr[i] = 0.f;
  }
  const float lastv = X[(size_t)(wavebase + c15)*24 + 22];

  // w0[o] = sum_t query[t]*emb[t][o]; quad q holds t in [4q,4q+4) -> shfl reduce
  float w0[TOUT];
  #pragma unroll
  for (int o = 0; o < TOUT; ++o) w0[o] = 0.f;
  if (quad < 3){
    #pragma unroll
    for (int tt = 0; tt < 4; ++tt){
      const int t = quad*4 + tt;
      const float qv = xr[2*tt];
      #pragma unroll
      for (int o = 0; o < TOUT; ++o) w0[o] = fmaf(qv, wp.emb[t*TOUT + o], w0[o]);
    }
  }
  #pragma unroll
  for (int o = 0; o < TOUT; ++o){
    w0[o] += __shfl_xor(w0[o], 16, 64);
    w0[o] += __shfl_xor(w0[o], 32, 64);
  }

  // A-frag for hv GEMM (quad3 = exact-1.0 bias row k=24)
  half8 axh = {0,0,0,0,0,0,0,0};
  if (quad < 3){
    #pragma unroll
    for (int j2 = 0; j2 < 8; ++j2) axh[j2] = (_Float16)xr[j2];
  } else {
    axh[0] = (_Float16)1.0f;
  }

  float msx = -1e30f, dsum = 0.f;
  float num[TOUT];
  #pragma unroll
  for (int o = 0; o < TOUT; ++o) num[o] = 0.f;

  #pragma unroll 1
  for (int c = 0; c < CC; ++c){
    const float l1b = wp.l1b[c];

    // ======== encoder phase ========
    __syncthreads();
    {
      const float* whh = wp.ewhh + c*12288;
      for (int ch = tid; ch < 24*64; ch += 256){
        const int tile = ch >> 6, L = ch & 63;
        const int a = tile >> 1, kt = tile & 1;
        const int col = L & 15, qd = L >> 4;
        const float* src = whh + (rowbase(a) + col)*64 + kt*32 + qd*8;
        f32x4 p0 = *(const f32x4*)src, p1 = *(const f32x4*)(src + 4);
        half8 h;
        h[0]=(_Float16)p0[0]; h[1]=(_Float16)p0[1]; h[2]=(_Float16)p0[2]; h[3]=(_Float16)p0[3];
        h[4]=(_Float16)p1[0]; h[5]=(_Float16)p1[1]; h[6]=(_Float16)p1[2]; h[7]=(_Float16)p1[3];
        *(half8*)(tiles_s + tile*512 + L*8) = h;
      }
      // hv tiles from l2w/l2b: slot 24+nt; B[k=2t+f2][col] = (f2==f)*w2[j][t], row24=b2[j]
      for (int ch = tid; ch < 2*64; ch += 256){
        const int nt = ch >> 6, L = ch & 63;
        const int col = L & 15, qd = L >> 4;
        const int j_ = nt*8 + (col >> 1), f_ = col & 1;
        const bool okc = (nt == 0) || (col < 8);
        half8 h;
        #pragma unroll
        for (int jj = 0; jj < 8; ++jj){
          const int k = qd*8 + jj;
          float v = 0.f;
          if (okc){
            if (k < 24){
              const int t = k >> 1, f2 = k & 1;
              if (f2 == f_) v = wp.l2w[c*144 + j_*12 + t];
            } else if (k == 24){
              v = wp.l2b[c*12 + j_];
            }
          }
          h[jj] = (_Float16)v;
        }
        *(half8*)(tiles_s + (24 + nt)*512 + L*8) = h;
      }
    }
    __syncthreads();

    // enc aug regs (per-lane, statically indexed -> real VGPRs)
    float aw0[8], aw1[8], ab[8], ghb[4], gxw0[4], gxw1[4], gxb[4];
    #pragma unroll
    for (int a = 0; a < 8; ++a){
      const int j = (a & 3)*16 + c15 + (a >= 4 ? 64 : 0);
      aw0[a] = wp.ewih[c*384 + 2*j];
      aw1[a] = wp.ewih[c*384 + 2*j + 1];
      ab[a]  = wp.ebih[c*192 + j] + wp.ebhh[c*192 + j];
    }
    #pragma unroll
    for (int q = 0; q < 4; ++q){
      const int j = 128 + q*16 + c15;
      ghb[q]  = wp.ebhh[c*192 + j];
      gxw0[q] = wp.ewih[c*384 + 2*j];
      gxw1[q] = wp.ewih[c*384 + 2*j + 1];
      gxb[q]  = wp.ebih[c*192 + j];
    }

    // hv GEMM: inputs for all 12 encoder steps
    #pragma unroll
    for (int nt = 0; nt < 2; ++nt){
      f32x4 a = {0.f, 0.f, 0.f, 0.f};
      const half8 bh = *(const half8*)(tiles_s + (24 + nt)*512 + lane8);
      a = MFMAH(axh, bh, a);
      if (nt == 0 || c15 < 8){
        #pragma unroll
        for (int r = 0; r < 4; ++r)
          hv[(quad*4 + r)*26 + nt*16 + c15] = a[r];
      }
    }

    float hc[16];
    #pragma unroll
    for (int q = 0; q < 16; ++q) hc[q] = 0.f;
    half8 ahi[2];
    ahi[0] = (half8){0,0,0,0,0,0,0,0};
    ahi[1] = (half8){0,0,0,0,0,0,0,0};

    const int steps = 3 + c;
    #pragma unroll 1
    for (int j = 0; j < steps; ++j){
      float x0[4], x1[4];
      #pragma unroll
      for (int r = 0; r < 4; ++r){
        const float2 p = *(const float2*)&hv[(quad*4 + r)*26 + 2*j];
        x0[r] = p.x; x1[r] = p.y;
      }
      run_step(x0, x1, tiles_s, aw0, aw1, ab, ghb, gxw0, gxw1, gxb,
               hc, ahi, hb, c15, quad, lane8);
    }

    // ======== decoder phase ========
    __syncthreads();
    {
      const float* whh = wp.dwhh + c*12288;
      for (int ch = tid; ch < 24*64; ch += 256){
        const int tile = ch >> 6, L = ch & 63;
        const int a = tile >> 1, kt = tile & 1;
        const int col = L & 15, qd = L >> 4;
        const float* src = whh + (rowbase(a) + col)*64 + kt*32 + qd*8;
        f32x4 p0 = *(const f32x4*)src, p1 = *(const f32x4*)(src + 4);
        half8 h;
        h[0]=(_Float16)p0[0]; h[1]=(_Float16)p0[1]; h[2]=(_Float16)p0[2]; h[3]=(_Float16)p0[3];
        h[4]=(_Float16)p1[0]; h[5]=(_Float16)p1[1]; h[6]=(_Float16)p1[2]; h[7]=(_Float16)p1[3];
        *(half8*)(tiles_s + tile*512 + L*8) = h;
      }
      // v tiles (l1w in col 0): slots 24..25
      for (int ch = tid; ch < 2*64; ch += 256){
        const int kt = ch >> 6, L = ch & 63;
        const int col = L & 15, qd = L >> 4;
        half8 h = {0,0,0,0,0,0,0,0};
        if (col == 0){
          const float* src = wp.l1w + c*64 + kt*32 + qd*8;
          f32x4 p0 = *(const f32x4*)src, p1 = *(const f32x4*)(src + 4);
          h[0]=(_Float16)p0[0]; h[1]=(_Float16)p0[1]; h[2]=(_Float16)p0[2]; h[3]=(_Float16)p0[3];
          h[4]=(_Float16)p1[0]; h[5]=(_Float16)p1[1]; h[6]=(_Float16)p1[2]; h[7]=(_Float16)p1[3];
        }
        *(half8*)(tiles_s + (24 + kt)*512 + L*8) = h;
      }
    }
    __syncthreads();

    // dec aug regs
    #pragma unroll
    for (int a = 0; a < 8; ++a){
      const int j = (a & 3)*16 + c15 + (a >= 4 ? 64 : 0);
      aw0[a] = wp.dwih[c*192 + j];
      aw1[a] = 0.f;
      ab[a]  = wp.dbih[c*192 + j] + wp.dbhh[c*192 + j];
    }
    #pragma unroll
    for (int q = 0; q < 4; ++q){
      const int j = 128 + q*16 + c15;
      ghb[q]  = wp.dbhh[c*192 + j];
      gxw0[q] = wp.dwih[c*192 + j];
      gxw1[q] = 0.f;
      gxb[q]  = wp.dbih[c*192 + j];
    }

    if (quad == 0) lvb[c15] = lastv;

    const float zx1[4] = {0.f, 0.f, 0.f, 0.f};
    #pragma unroll 1
    for (int i = 0; i < TOUT; ++i){
      if (i > 0){
        f32x4 accv = {l1b, l1b, l1b, l1b};
        #pragma unroll
        for (int kt = 0; kt < 2; ++kt){
          const half8 bh = *(const half8*)(tiles_s + (24 + kt)*512 + lane8);
          accv = MFMAH(ahi[kt], bh, accv);
        }
        if (c15 == 0){
          #pragma unroll
          for (int r = 0; r < 4; ++r){
            va[(quad*4 + r)*12 + (i - 1)] = accv[r];
            lvb[quad*4 + r] = accv[r];
          }
        }
      }
      float x0[4];
      #pragma unroll
      for (int r = 0; r < 4; ++r) x0[r] = lvb[quad*4 + r];
      run_step(x0, zx1, tiles_s, aw0, aw1, ab, ghb, gxw0, gxw1, gxb,
               hc, ahi, hb, c15, quad, lane8);
    }
    {
      f32x4 accv = {l1b, l1b, l1b, l1b};
      #pragma unroll
      for (int kt = 0; kt < 2; ++kt){
        const half8 bh = *(const half8*)(tiles_s + (24 + kt)*512 + lane8);
        accv = MFMAH(ahi[kt], bh, accv);
      }
      if (c15 == 0){
        #pragma unroll
        for (int r = 0; r < 4; ++r) va[(quad*4 + r)*12 + 11] = accv[r];
      }
    }

    // online softmax update (per-lane, m=c15)
    {
      float l = 0.f;
      #pragma unroll
      for (int o = 0; o < TOUT; ++o) l = fmaf(w0[o], va[c15*12 + o], l);
      const float nmx = fmaxf(msx, l);
      const float aa = __expf(msx - nmx);
      const float ee = __expf(l - nmx);
      dsum = dsum*aa + ee;
      #pragma unroll
      for (int o = 0; o < TOUT; ++o) num[o] = num[o]*aa + va[c15*12 + o]*ee;
      msx = nmx;
    }
  }

  if (quad == 0){
    const float inv = 1.0f / dsum;
    #pragma unroll
    for (int o = 0; o < TOUT; ++o)
      out[(size_t)(wavebase + c15)*12 + o] = num[o]*inv;
  }
}

extern "C" void kernel_launch(void* const* d_in, const int* in_sizes, int n_in,
                              void* d_out, int out_size, void* d_ws, size_t ws_size,
                              hipStream_t stream) {
  int iX = 1, iW = 2;
  for (int i = 0; i < n_in; ++i){
    if (in_sizes[i] == 3145728) iX = i;
    if (in_sizes[i] == 3840)   { iW = i; break; }
  }
  W wp;
  wp.ewih = (const float*)d_in[iW + 0];
  wp.ewhh = (const float*)d_in[iW + 1];
  wp.ebih = (const float*)d_in[iW + 2];
  wp.ebhh = (const float*)d_in[iW + 3];
  wp.dwih = (const float*)d_in[iW + 4];
  wp.dwhh = (const float*)d_in[iW + 5];
  wp.dbih = (const float*)d_in[iW + 6];
  wp.dbhh = (const float*)d_in[iW + 7];
  wp.l1w  = (const float*)d_in[iW + 8];
  wp.l1b  = (const float*)d_in[iW + 9];
  wp.l2w  = (const float*)d_in[iW + 10];
  wp.l2b  = (const float*)d_in[iW + 11];
  wp.emb  = (const float*)d_in[iW + 12];

  rnn_mfma5<<<BNTOT / 64, 256, 0, stream>>>(
      (const float*)d_in[iX], wp, (float*)d_out);
}

// Round 10
// 3114.470 us; speedup vs baseline: 2.8332x; 2.8332x over previous
//
#include <hip/hip_runtime.h>

typedef __attribute__((ext_vector_type(8))) _Float16 half8;
typedef __attribute__((ext_vector_type(4))) float f32x4;

#define HH 64
#define TT 12
#define TOUT 12
#define CC 10
#define BNTOT 131072

__device__ __forceinline__ float sigm(float x){
  return __builtin_amdgcn_rcpf(1.0f + __expf(-x));
}
__device__ __forceinline__ float tanh_f(float x){
  return 1.0f - 2.0f * __builtin_amdgcn_rcpf(1.0f + __expf(2.0f * x));
}

struct W {
  const float* ewih; const float* ewhh; const float* ebih; const float* ebhh;
  const float* dwih; const float* dwhh; const float* dbih; const float* dbhh;
  const float* l1w;  const float* l1b;  const float* l2w;  const float* l2b;
  const float* emb;
};

#define MFMAH(A,B,C) __builtin_amdgcn_mfma_f32_16x16x32_f16((A),(B),(C),0,0,0)

// group a (0..11) -> w_hh row base: a0-3 pre_r, a4-7 pre_z, a8-11 gh_n
__device__ __forceinline__ int rowbase(int a){
  return (a < 4) ? a*16 : (a < 8) ? 64 + (a - 4)*16 : 128 + (a - 8)*16;
}

// One GRU step. aug path fp32 VALU (exact); h-part single fp16 MFMA per (a,kt).
// All per-step operands come from LDS (24 KB shared tiles) or registers.
__device__ __forceinline__ void run_step(
    const float x0[4], const float x1[4],
    const _Float16* __restrict__ tiles,
    const float aw0[8], const float aw1[8], const float ab[8],
    const float ghb[4], const float gxw0[4], const float gxw1[4], const float gxb[4],
    float hc[16], half8 ahi[2], float* hb,
    int c15, int quad, int lane8)
{
  f32x4 acc[12];
  #pragma unroll
  for (int a = 0; a < 8; ++a){
    #pragma unroll
    for (int r = 0; r < 4; ++r)
      acc[a][r] = fmaf(x0[r], aw0[a], fmaf(x1[r], aw1[a], ab[a]));
  }
  #pragma unroll
  for (int q = 0; q < 4; ++q){
    #pragma unroll
    for (int r = 0; r < 4; ++r) acc[8 + q][r] = ghb[q];
  }
  #pragma unroll
  for (int a = 0; a < 12; ++a){
    #pragma unroll
    for (int kt = 0; kt < 2; ++kt){
      const half8 bh = *(const half8*)(tiles + (a*2 + kt)*512 + lane8);
      acc[a] = MFMAH(ahi[kt], bh, acc[a]);
    }
  }
  // gates (gx_n inline fp32) + transpose via hb (stride 68, 16B-aligned rows)
  #pragma unroll
  for (int q = 0; q < 4; ++q){
    #pragma unroll
    for (int r = 0; r < 4; ++r){
      const float pr = acc[q][r], pz = acc[4 + q][r], gh = acc[8 + q][r];
      const float gx = fmaf(x0[r], gxw0[q], fmaf(x1[r], gxw1[q], gxb[q]));
      const float rr = sigm(pr), zz = sigm(pz);
      const float nn = tanh_f(fmaf(rr, gh, gx));
      const float hn = (1.0f - zz)*nn + zz*hc[q*4 + r];
      hc[q*4 + r] = hn;
      hb[(quad*4 + r)*68 + q*16 + c15] = hn;
    }
  }
  const int m = c15, q8 = quad*8;
  #pragma unroll
  for (int kt = 0; kt < 2; ++kt){
    const f32x4* p = (const f32x4*)&hb[m*68 + kt*32 + q8];
    f32x4 a = p[0], b = p[1];
    half8 h;
    h[0]=(_Float16)a[0]; h[1]=(_Float16)a[1]; h[2]=(_Float16)a[2]; h[3]=(_Float16)a[3];
    h[4]=(_Float16)b[0]; h[5]=(_Float16)b[1]; h[6]=(_Float16)b[2]; h[7]=(_Float16)b[3];
    ahi[kt] = h;
  }
}

__global__ __launch_bounds__(256, 2) void rnn_mfma6(
    const float* __restrict__ X, W wp, float* __restrict__ out)
{
  __shared__ __align__(16) _Float16 tiles_s[26*512];   // 24 whh tiles + 2 hv/v
  __shared__ __align__(16) float wbuf_s[4*1712];       // per-wave hb/hv/va/lvb

  const int tid = threadIdx.x;
  const int wid = tid >> 6, lane = tid & 63;
  const int quad = lane >> 4, c15 = lane & 15;
  const int lane8 = lane*8;
  float* wl  = wbuf_s + wid*1712;
  float* hb  = wl;                 // 16*68
  float* hv  = wl + 1088;          // 16*26 (stride 26: total LDS fits 3 blocks/CU)
  float* va  = wl + 1504;          // 16*12
  float* lvb = wl + 1696;          // 16
  const int wavebase = (blockIdx.x*4 + wid)*16;

  // ---- X row -> regs: lane holds sample m=c15, elements [quad*8, quad*8+8) ----
  float xr[8];
  if (quad < 3){
    const float* xp = X + (size_t)(wavebase + c15)*24 + quad*8;
    f32x4 p0 = *(const f32x4*)xp, p1 = *(const f32x4*)(xp + 4);
    xr[0]=p0[0]; xr[1]=p0[1]; xr[2]=p0[2]; xr[3]=p0[3];
    xr[4]=p1[0]; xr[5]=p1[1]; xr[6]=p1[2]; xr[7]=p1[3];
  } else {
    #pragma unroll
    for (int i = 0; i < 8; ++i) xr[i] = 0.f;
  }
  const float lastv = X[(size_t)(wavebase + c15)*24 + 22];

  // w0[o] = sum_t query[t]*emb[t][o]; quad q holds t in [4q,4q+4) -> shfl reduce
  float w0[TOUT];
  #pragma unroll
  for (int o = 0; o < TOUT; ++o) w0[o] = 0.f;
  if (quad < 3){
    #pragma unroll
    for (int tt = 0; tt < 4; ++tt){
      const int t = quad*4 + tt;
      const float qv = xr[2*tt];
      #pragma unroll
      for (int o = 0; o < TOUT; ++o) w0[o] = fmaf(qv, wp.emb[t*TOUT + o], w0[o]);
    }
  }
  #pragma unroll
  for (int o = 0; o < TOUT; ++o){
    w0[o] += __shfl_xor(w0[o], 16, 64);
    w0[o] += __shfl_xor(w0[o], 32, 64);
  }

  // A-frag for hv GEMM (quad3 = exact-1.0 bias row k=24)
  half8 axh = {0,0,0,0,0,0,0,0};
  if (quad < 3){
    #pragma unroll
    for (int j2 = 0; j2 < 8; ++j2) axh[j2] = (_Float16)xr[j2];
  } else {
    axh[0] = (_Float16)1.0f;
  }

  float msx = -1e30f, dsum = 0.f;
  float num[TOUT];
  #pragma unroll
  for (int o = 0; o < TOUT; ++o) num[o] = 0.f;

  #pragma unroll 1
  for (int c = 0; c < CC; ++c){
    const float l1b = wp.l1b[c];

    // ======== encoder phase ========
    __syncthreads();
    {
      const float* whh = wp.ewhh + c*12288;
      for (int ch = tid; ch < 24*64; ch += 256){
        const int tile = ch >> 6, L = ch & 63;
        const int a = tile >> 1, kt = tile & 1;
        const int col = L & 15, qd = L >> 4;
        const float* src = whh + (rowbase(a) + col)*64 + kt*32 + qd*8;
        f32x4 p0 = *(const f32x4*)src, p1 = *(const f32x4*)(src + 4);
        half8 h;
        h[0]=(_Float16)p0[0]; h[1]=(_Float16)p0[1]; h[2]=(_Float16)p0[2]; h[3]=(_Float16)p0[3];
        h[4]=(_Float16)p1[0]; h[5]=(_Float16)p1[1]; h[6]=(_Float16)p1[2]; h[7]=(_Float16)p1[3];
        *(half8*)(tiles_s + tile*512 + L*8) = h;
      }
      // hv tiles from l2w/l2b: slot 24+nt; B[k=2t+f2][col] = (f2==f)*w2[j][t], row24=b2[j]
      for (int ch = tid; ch < 2*64; ch += 256){
        const int nt = ch >> 6, L = ch & 63;
        const int col = L & 15, qd = L >> 4;
        const int j_ = nt*8 + (col >> 1), f_ = col & 1;
        const bool okc = (nt == 0) || (col < 8);
        half8 h;
        #pragma unroll
        for (int jj = 0; jj < 8; ++jj){
          const int k = qd*8 + jj;
          float v = 0.f;
          if (okc){
            if (k < 24){
              const int t = k >> 1, f2 = k & 1;
              if (f2 == f_) v = wp.l2w[c*144 + j_*12 + t];
            } else if (k == 24){
              v = wp.l2b[c*12 + j_];
            }
          }
          h[jj] = (_Float16)v;
        }
        *(half8*)(tiles_s + (24 + nt)*512 + L*8) = h;
      }
    }
    __syncthreads();

    // enc aug regs (per-lane, statically indexed -> real VGPRs)
    float aw0[8], aw1[8], ab[8], ghb[4], gxw0[4], gxw1[4], gxb[4];
    #pragma unroll
    for (int a = 0; a < 8; ++a){
      const int j = (a & 3)*16 + c15 + (a >= 4 ? 64 : 0);
      aw0[a] = wp.ewih[c*384 + 2*j];
      aw1[a] = wp.ewih[c*384 + 2*j + 1];
      ab[a]  = wp.ebih[c*192 + j] + wp.ebhh[c*192 + j];
    }
    #pragma unroll
    for (int q = 0; q < 4; ++q){
      const int j = 128 + q*16 + c15;
      ghb[q]  = wp.ebhh[c*192 + j];
      gxw0[q] = wp.ewih[c*384 + 2*j];
      gxw1[q] = wp.ewih[c*384 + 2*j + 1];
      gxb[q]  = wp.ebih[c*192 + j];
    }

    // hv GEMM: inputs for all 12 encoder steps
    #pragma unroll
    for (int nt = 0; nt < 2; ++nt){
      f32x4 a = {0.f, 0.f, 0.f, 0.f};
      const half8 bh = *(const half8*)(tiles_s + (24 + nt)*512 + lane8);
      a = MFMAH(axh, bh, a);
      if (nt == 0 || c15 < 8){
        #pragma unroll
        for (int r = 0; r < 4; ++r)
          hv[(quad*4 + r)*26 + nt*16 + c15] = a[r];
      }
    }

    float hc[16];
    #pragma unroll
    for (int q = 0; q < 16; ++q) hc[q] = 0.f;
    half8 ahi[2];
    ahi[0] = (half8){0,0,0,0,0,0,0,0};
    ahi[1] = (half8){0,0,0,0,0,0,0,0};

    const int steps = 3 + c;
    #pragma unroll 1
    for (int j = 0; j < steps; ++j){
      float x0[4], x1[4];
      #pragma unroll
      for (int r = 0; r < 4; ++r){
        const float2 p = *(const float2*)&hv[(quad*4 + r)*26 + 2*j];
        x0[r] = p.x; x1[r] = p.y;
      }
      run_step(x0, x1, tiles_s, aw0, aw1, ab, ghb, gxw0, gxw1, gxb,
               hc, ahi, hb, c15, quad, lane8);
    }

    // ======== decoder phase ========
    __syncthreads();
    {
      const float* whh = wp.dwhh + c*12288;
      for (int ch = tid; ch < 24*64; ch += 256){
        const int tile = ch >> 6, L = ch & 63;
        const int a = tile >> 1, kt = tile & 1;
        const int col = L & 15, qd = L >> 4;
        const float* src = whh + (rowbase(a) + col)*64 + kt*32 + qd*8;
        f32x4 p0 = *(const f32x4*)src, p1 = *(const f32x4*)(src + 4);
        half8 h;
        h[0]=(_Float16)p0[0]; h[1]=(_Float16)p0[1]; h[2]=(_Float16)p0[2]; h[3]=(_Float16)p0[3];
        h[4]=(_Float16)p1[0]; h[5]=(_Float16)p1[1]; h[6]=(_Float16)p1[2]; h[7]=(_Float16)p1[3];
        *(half8*)(tiles_s + tile*512 + L*8) = h;
      }
      // v tiles (l1w in col 0): slots 24..25
      for (int ch = tid; ch < 2*64; ch += 256){
        const int kt = ch >> 6, L = ch & 63;
        const int col = L & 15, qd = L >> 4;
        half8 h = {0,0,0,0,0,0,0,0};
        if (col == 0){
          const float* src = wp.l1w + c*64 + kt*32 + qd*8;
          f32x4 p0 = *(const f32x4*)src, p1 = *(const f32x4*)(src + 4);
          h[0]=(_Float16)p0[0]; h[1]=(_Float16)p0[1]; h[2]=(_Float16)p0[2]; h[3]=(_Float16)p0[3];
          h[4]=(_Float16)p1[0]; h[5]=(_Float16)p1[1]; h[6]=(_Float16)p1[2]; h[7]=(_Float16)p1[3];
        }
        *(half8*)(tiles_s + (24 + kt)*512 + L*8) = h;
      }
    }
    __syncthreads();

    // dec aug regs
    #pragma unroll
    for (int a = 0; a < 8; ++a){
      const int j = (a & 3)*16 + c15 + (a >= 4 ? 64 : 0);
      aw0[a] = wp.dwih[c*192 + j];
      aw1[a] = 0.f;
      ab[a]  = wp.dbih[c*192 + j] + wp.dbhh[c*192 + j];
    }
    #pragma unroll
    for (int q = 0; q < 4; ++q){
      const int j = 128 + q*16 + c15;
      ghb[q]  = wp.dbhh[c*192 + j];
      gxw0[q] = wp.dwih[c*192 + j];
      gxw1[q] = 0.f;
      gxb[q]  = wp.dbih[c*192 + j];
    }

    if (quad == 0) lvb[c15] = lastv;

    const float zx1[4] = {0.f, 0.f, 0.f, 0.f};
    #pragma unroll 1
    for (int i = 0; i < TOUT; ++i){
      if (i > 0){
        f32x4 accv = {l1b, l1b, l1b, l1b};
        #pragma unroll
        for (int kt = 0; kt < 2; ++kt){
          const half8 bh = *(const half8*)(tiles_s + (24 + kt)*512 + lane8);
          accv = MFMAH(ahi[kt], bh, accv);
        }
        if (c15 == 0){
          #pragma unroll
          for (int r = 0; r < 4; ++r){
            va[(quad*4 + r)*12 + (i - 1)] = accv[r];
            lvb[quad*4 + r] = accv[r];
          }
        }
      }
      float x0[4];
      #pragma unroll
      for (int r = 0; r < 4; ++r) x0[r] = lvb[quad*4 + r];
      run_step(x0, zx1, tiles_s, aw0, aw1, ab, ghb, gxw0, gxw1, gxb,
               hc, ahi, hb, c15, quad, lane8);
    }
    {
      f32x4 accv = {l1b, l1b, l1b, l1b};
      #pragma unroll
      for (int kt = 0; kt < 2; ++kt){
        const half8 bh = *(const half8*)(tiles_s + (24 + kt)*512 + lane8);
        accv = MFMAH(ahi[kt], bh, accv);
      }
      if (c15 == 0){
        #pragma unroll
        for (int r = 0; r < 4; ++r) va[(quad*4 + r)*12 + 11] = accv[r];
      }
    }

    // online softmax update (per-lane, m=c15)
    {
      float l = 0.f;
      #pragma unroll
      for (int o = 0; o < TOUT; ++o) l = fmaf(w0[o], va[c15*12 + o], l);
      const float nmx = fmaxf(msx, l);
      const float aa = __expf(msx - nmx);
      const float ee = __expf(l - nmx);
      dsum = dsum*aa + ee;
      #pragma unroll
      for (int o = 0; o < TOUT; ++o) num[o] = num[o]*aa + va[c15*12 + o]*ee;
      msx = nmx;
    }
  }

  if (quad == 0){
    const float inv = 1.0f / dsum;
    #pragma unroll
    for (int o = 0; o < TOUT; ++o)
      out[(size_t)(wavebase + c15)*12 + o] = num[o]*inv;
  }
}

extern "C" void kernel_launch(void* const* d_in, const int* in_sizes, int n_in,
                              void* d_out, int out_size, void* d_ws, size_t ws_size,
                              hipStream_t stream) {
  int iX = 1, iW = 2;
  for (int i = 0; i < n_in; ++i){
    if (in_sizes[i] == 3145728) iX = i;
    if (in_sizes[i] == 3840)   { iW = i; break; }
  }
  W wp;
  wp.ewih = (const float*)d_in[iW + 0];
  wp.ewhh = (const float*)d_in[iW + 1];
  wp.ebih = (const float*)d_in[iW + 2];
  wp.ebhh = (const float*)d_in[iW + 3];
  wp.dwih = (const float*)d_in[iW + 4];
  wp.dwhh = (const float*)d_in[iW + 5];
  wp.dbih = (const float*)d_in[iW + 6];
  wp.dbhh = (const float*)d_in[iW + 7];
  wp.l1w  = (const float*)d_in[iW + 8];
  wp.l1b  = (const float*)d_in[iW + 9];
  wp.l2w  = (const float*)d_in[iW + 10];
  wp.l2b  = (const float*)d_in[iW + 11];
  wp.emb  = (const float*)d_in[iW + 12];

  rnn_mfma6<<<BNTOT / 64, 256, 0, stream>>>(
      (const float*)d_in[iX], wp, (float*)d_out);
}

// Round 11
// 3075.159 us; speedup vs baseline: 2.8695x; 1.0128x over previous
//
#include <hip/hip_runtime.h>

typedef __attribute__((ext_vector_type(8))) _Float16 half8;
typedef __attribute__((ext_vector_type(4))) float f32x4;

#define HH 64
#define TT 12
#define TOUT 12
#define CC 10
#define BNTOT 131072

__device__ __forceinline__ float sigm(float x){
  return __builtin_amdgcn_rcpf(1.0f + __expf(-x));
}
__device__ __forceinline__ float tanh_f(float x){
  return 1.0f - 2.0f * __builtin_amdgcn_rcpf(1.0f + __expf(2.0f * x));
}

struct W {
  const float* ewih; const float* ewhh; const float* ebih; const float* ebhh;
  const float* dwih; const float* dwhh; const float* dbih; const float* dbhh;
  const float* l1w;  const float* l1b;  const float* l2w;  const float* l2b;
  const float* emb;
};

#define MFMAH(A,B,C) __builtin_amdgcn_mfma_f32_16x16x32_f16((A),(B),(C),0,0,0)

// group a (0..11) -> w_hh row base: a0-3 pre_r, a4-7 pre_z, a8-11 gh_n
__device__ __forceinline__ int rowbase(int a){
  return (a < 4) ? a*16 : (a < 8) ? 64 + (a - 4)*16 : 128 + (a - 8)*16;
}

// One GRU step. aug path fp32 VALU (exact); h-part single fp16 MFMA per (a,kt).
// hb is fp16 (stride 72 halves): store-side fp32->fp16 cast == old load-side
// convert, and the A-frag rebuild becomes one raw ds_read_b128 per kt.
__device__ __forceinline__ void run_step(
    const float x0[4], const float x1[4],
    const _Float16* __restrict__ tiles,
    const float aw0[8], const float aw1[8], const float ab[8],
    const float ghb[4], const float gxw0[4], const float gxw1[4], const float gxb[4],
    float hc[16], half8 ahi[2], _Float16* hb,
    int c15, int quad, int lane8)
{
  f32x4 acc[12];
  #pragma unroll
  for (int a = 0; a < 8; ++a){
    #pragma unroll
    for (int r = 0; r < 4; ++r)
      acc[a][r] = fmaf(x0[r], aw0[a], fmaf(x1[r], aw1[a], ab[a]));
  }
  #pragma unroll
  for (int q = 0; q < 4; ++q){
    #pragma unroll
    for (int r = 0; r < 4; ++r) acc[8 + q][r] = ghb[q];
  }
  #pragma unroll
  for (int a = 0; a < 12; ++a){
    #pragma unroll
    for (int kt = 0; kt < 2; ++kt){
      const half8 bh = *(const half8*)(tiles + (a*2 + kt)*512 + lane8);
      acc[a] = MFMAH(ahi[kt], bh, acc[a]);
    }
  }
  // gates (gx_n inline fp32) + fp16 transpose via hb
  #pragma unroll
  for (int q = 0; q < 4; ++q){
    #pragma unroll
    for (int r = 0; r < 4; ++r){
      const float pr = acc[q][r], pz = acc[4 + q][r], gh = acc[8 + q][r];
      const float gx = fmaf(x0[r], gxw0[q], fmaf(x1[r], gxw1[q], gxb[q]));
      const float rr = sigm(pr), zz = sigm(pz);
      const float nn = tanh_f(fmaf(rr, gh, gx));
      const float hn = (1.0f - zz)*nn + zz*hc[q*4 + r];
      hc[q*4 + r] = hn;
      hb[(quad*4 + r)*72 + q*16 + c15] = (_Float16)hn;
    }
  }
  #pragma unroll
  for (int kt = 0; kt < 2; ++kt)
    ahi[kt] = *(const half8*)&hb[c15*72 + kt*32 + quad*8];
}

__global__ __launch_bounds__(256, 2) void rnn_mfma7(
    const float* __restrict__ X, W wp, float* __restrict__ out)
{
  __shared__ __align__(16) _Float16 tiles_s[26*512];   // 24 whh tiles + 2 hv/v
  __shared__ __align__(16) _Float16 hbuf_s[4*1152];    // per-wave fp16 hb (16x72)
  __shared__ __align__(16) float wbuf_s[4*624];        // per-wave hv/va/lvb

  const int tid = threadIdx.x;
  const int wid = tid >> 6, lane = tid & 63;
  const int quad = lane >> 4, c15 = lane & 15;
  const int lane8 = lane*8;
  _Float16* hb = hbuf_s + wid*1152;
  float* wl  = wbuf_s + wid*624;
  float* hv  = wl;                 // 16*26
  float* va  = wl + 416;           // 16*12
  float* lvb = wl + 608;           // 16
  const int wavebase = (blockIdx.x*4 + wid)*16;

  // ---- X row -> regs: lane holds sample m=c15, elements [quad*8, quad*8+8) ----
  float xr[8];
  if (quad < 3){
    const float* xp = X + (size_t)(wavebase + c15)*24 + quad*8;
    f32x4 p0 = *(const f32x4*)xp, p1 = *(const f32x4*)(xp + 4);
    xr[0]=p0[0]; xr[1]=p0[1]; xr[2]=p0[2]; xr[3]=p0[3];
    xr[4]=p1[0]; xr[5]=p1[1]; xr[6]=p1[2]; xr[7]=p1[3];
  } else {
    #pragma unroll
    for (int i = 0; i < 8; ++i) xr[i] = 0.f;
  }
  const float lastv = X[(size_t)(wavebase + c15)*24 + 22];

  // w0[o] = sum_t query[t]*emb[t][o]; quad q holds t in [4q,4q+4) -> shfl reduce
  float w0[TOUT];
  #pragma unroll
  for (int o = 0; o < TOUT; ++o) w0[o] = 0.f;
  if (quad < 3){
    #pragma unroll
    for (int tt = 0; tt < 4; ++tt){
      const int t = quad*4 + tt;
      const float qv = xr[2*tt];
      #pragma unroll
      for (int o = 0; o < TOUT; ++o) w0[o] = fmaf(qv, wp.emb[t*TOUT + o], w0[o]);
    }
  }
  #pragma unroll
  for (int o = 0; o < TOUT; ++o){
    w0[o] += __shfl_xor(w0[o], 16, 64);
    w0[o] += __shfl_xor(w0[o], 32, 64);
  }

  // A-frag for hv GEMM (quad3 = exact-1.0 bias row k=24)
  half8 axh = {0,0,0,0,0,0,0,0};
  if (quad < 3){
    #pragma unroll
    for (int j2 = 0; j2 < 8; ++j2) axh[j2] = (_Float16)xr[j2];
  } else {
    axh[0] = (_Float16)1.0f;
  }

  float msx = -1e30f, dsum = 0.f;
  float num[TOUT];
  #pragma unroll
  for (int o = 0; o < TOUT; ++o) num[o] = 0.f;

  #pragma unroll 1
  for (int c = 0; c < CC; ++c){
    const float l1b = wp.l1b[c];

    // ======== encoder phase ========
    __syncthreads();
    {
      const float* whh = wp.ewhh + c*12288;
      for (int ch = tid; ch < 24*64; ch += 256){
        const int tile = ch >> 6, L = ch & 63;
        const int a = tile >> 1, kt = tile & 1;
        const int col = L & 15, qd = L >> 4;
        const float* src = whh + (rowbase(a) + col)*64 + kt*32 + qd*8;
        f32x4 p0 = *(const f32x4*)src, p1 = *(const f32x4*)(src + 4);
        half8 h;
        h[0]=(_Float16)p0[0]; h[1]=(_Float16)p0[1]; h[2]=(_Float16)p0[2]; h[3]=(_Float16)p0[3];
        h[4]=(_Float16)p1[0]; h[5]=(_Float16)p1[1]; h[6]=(_Float16)p1[2]; h[7]=(_Float16)p1[3];
        *(half8*)(tiles_s + tile*512 + L*8) = h;
      }
      // hv tiles from l2w/l2b: slot 24+nt; B[k=2t+f2][col] = (f2==f)*w2[j][t], row24=b2[j]
      for (int ch = tid; ch < 2*64; ch += 256){
        const int nt = ch >> 6, L = ch & 63;
        const int col = L & 15, qd = L >> 4;
        const int j_ = nt*8 + (col >> 1), f_ = col & 1;
        const bool okc = (nt == 0) || (col < 8);
        half8 h;
        #pragma unroll
        for (int jj = 0; jj < 8; ++jj){
          const int k = qd*8 + jj;
          float v = 0.f;
          if (okc){
            if (k < 24){
              const int t = k >> 1, f2 = k & 1;
              if (f2 == f_) v = wp.l2w[c*144 + j_*12 + t];
            } else if (k == 24){
              v = wp.l2b[c*12 + j_];
            }
          }
          h[jj] = (_Float16)v;
        }
        *(half8*)(tiles_s + (24 + nt)*512 + L*8) = h;
      }
    }
    __syncthreads();

    // enc aug regs (per-lane, statically indexed -> real VGPRs)
    float aw0[8], aw1[8], ab[8], ghb[4], gxw0[4], gxw1[4], gxb[4];
    #pragma unroll
    for (int a = 0; a < 8; ++a){
      const int j = (a & 3)*16 + c15 + (a >= 4 ? 64 : 0);
      aw0[a] = wp.ewih[c*384 + 2*j];
      aw1[a] = wp.ewih[c*384 + 2*j + 1];
      ab[a]  = wp.ebih[c*192 + j] + wp.ebhh[c*192 + j];
    }
    #pragma unroll
    for (int q = 0; q < 4; ++q){
      const int j = 128 + q*16 + c15;
      ghb[q]  = wp.ebhh[c*192 + j];
      gxw0[q] = wp.ewih[c*384 + 2*j];
      gxw1[q] = wp.ewih[c*384 + 2*j + 1];
      gxb[q]  = wp.ebih[c*192 + j];
    }

    // hv GEMM: inputs for all 12 encoder steps
    #pragma unroll
    for (int nt = 0; nt < 2; ++nt){
      f32x4 a = {0.f, 0.f, 0.f, 0.f};
      const half8 bh = *(const half8*)(tiles_s + (24 + nt)*512 + lane8);
      a = MFMAH(axh, bh, a);
      if (nt == 0 || c15 < 8){
        #pragma unroll
        for (int r = 0; r < 4; ++r)
          hv[(quad*4 + r)*26 + nt*16 + c15] = a[r];
      }
    }

    float hc[16];
    #pragma unroll
    for (int q = 0; q < 16; ++q) hc[q] = 0.f;
    half8 ahi[2];
    ahi[0] = (half8){0,0,0,0,0,0,0,0};
    ahi[1] = (half8){0,0,0,0,0,0,0,0};

    const int steps = 3 + c;
    #pragma unroll 1
    for (int j = 0; j < steps; ++j){
      float x0[4], x1[4];
      #pragma unroll
      for (int r = 0; r < 4; ++r){
        const float2 p = *(const float2*)&hv[(quad*4 + r)*26 + 2*j];
        x0[r] = p.x; x1[r] = p.y;
      }
      run_step(x0, x1, tiles_s, aw0, aw1, ab, ghb, gxw0, gxw1, gxb,
               hc, ahi, hb, c15, quad, lane8);
    }

    // ======== decoder phase ========
    __syncthreads();
    {
      const float* whh = wp.dwhh + c*12288;
      for (int ch = tid; ch < 24*64; ch += 256){
        const int tile = ch >> 6, L = ch & 63;
        const int a = tile >> 1, kt = tile & 1;
        const int col = L & 15, qd = L >> 4;
        const float* src = whh + (rowbase(a) + col)*64 + kt*32 + qd*8;
        f32x4 p0 = *(const f32x4*)src, p1 = *(const f32x4*)(src + 4);
        half8 h;
        h[0]=(_Float16)p0[0]; h[1]=(_Float16)p0[1]; h[2]=(_Float16)p0[2]; h[3]=(_Float16)p0[3];
        h[4]=(_Float16)p1[0]; h[5]=(_Float16)p1[1]; h[6]=(_Float16)p1[2]; h[7]=(_Float16)p1[3];
        *(half8*)(tiles_s + tile*512 + L*8) = h;
      }
      // v tiles (l1w in col 0): slots 24..25
      for (int ch = tid; ch < 2*64; ch += 256){
        const int kt = ch >> 6, L = ch & 63;
        const int col = L & 15, qd = L >> 4;
        half8 h = {0,0,0,0,0,0,0,0};
        if (col == 0){
          const float* src = wp.l1w + c*64 + kt*32 + qd*8;
          f32x4 p0 = *(const f32x4*)src, p1 = *(const f32x4*)(src + 4);
          h[0]=(_Float16)p0[0]; h[1]=(_Float16)p0[1]; h[2]=(_Float16)p0[2]; h[3]=(_Float16)p0[3];
          h[4]=(_Float16)p1[0]; h[5]=(_Float16)p1[1]; h[6]=(_Float16)p1[2]; h[7]=(_Float16)p1[3];
        }
        *(half8*)(tiles_s + (24 + kt)*512 + L*8) = h;
      }
    }
    __syncthreads();

    // dec aug regs
    #pragma unroll
    for (int a = 0; a < 8; ++a){
      const int j = (a & 3)*16 + c15 + (a >= 4 ? 64 : 0);
      aw0[a] = wp.dwih[c*192 + j];
      aw1[a] = 0.f;
      ab[a]  = wp.dbih[c*192 + j] + wp.dbhh[c*192 + j];
    }
    #pragma unroll
    for (int q = 0; q < 4; ++q){
      const int j = 128 + q*16 + c15;
      ghb[q]  = wp.dbhh[c*192 + j];
      gxw0[q] = wp.dwih[c*192 + j];
      gxw1[q] = 0.f;
      gxb[q]  = wp.dbih[c*192 + j];
    }

    if (quad == 0) lvb[c15] = lastv;

    const float zx1[4] = {0.f, 0.f, 0.f, 0.f};
    #pragma unroll 1
    for (int i = 0; i < TOUT; ++i){
      if (i > 0){
        f32x4 accv = {l1b, l1b, l1b, l1b};
        #pragma unroll
        for (int kt = 0; kt < 2; ++kt){
          const half8 bh = *(const half8*)(tiles_s + (24 + kt)*512 + lane8);
          accv = MFMAH(ahi[kt], bh, accv);
        }
        if (c15 == 0){
          #pragma unroll
          for (int r = 0; r < 4; ++r){
            va[(quad*4 + r)*12 + (i - 1)] = accv[r];
            lvb[quad*4 + r] = accv[r];
          }
        }
      }
      float x0[4];
      #pragma unroll
      for (int r = 0; r < 4; ++r) x0[r] = lvb[quad*4 + r];
      run_step(x0, zx1, tiles_s, aw0, aw1, ab, ghb, gxw0, gxw1, gxb,
               hc, ahi, hb, c15, quad, lane8);
    }
    {
      f32x4 accv = {l1b, l1b, l1b, l1b};
      #pragma unroll
      for (int kt = 0; kt < 2; ++kt){
        const half8 bh = *(const half8*)(tiles_s + (24 + kt)*512 + lane8);
        accv = MFMAH(ahi[kt], bh, accv);
      }
      if (c15 == 0){
        #pragma unroll
        for (int r = 0; r < 4; ++r) va[(quad*4 + r)*12 + 11] = accv[r];
      }
    }

    // online softmax update (per-lane, m=c15)
    {
      float l = 0.f;
      #pragma unroll
      for (int o = 0; o < TOUT; ++o) l = fmaf(w0[o], va[c15*12 + o], l);
      const float nmx = fmaxf(msx, l);
      const float aa = __expf(msx - nmx);
      const float ee = __expf(l - nmx);
      dsum = dsum*aa + ee;
      #pragma unroll
      for (int o = 0; o < TOUT; ++o) num[o] = num[o]*aa + va[c15*12 + o]*ee;
      msx = nmx;
    }
  }

  if (quad == 0){
    const float inv = 1.0f / dsum;
    #pragma unroll
    for (int o = 0; o < TOUT; ++o)
      out[(size_t)(wavebase + c15)*12 + o] = num[o]*inv;
  }
}

extern "C" void kernel_launch(void* const* d_in, const int* in_sizes, int n_in,
                              void* d_out, int out_size, void* d_ws, size_t ws_size,
                              hipStream_t stream) {
  int iX = 1, iW = 2;
  for (int i = 0; i < n_in; ++i){
    if (in_sizes[i] == 3145728) iX = i;
    if (in_sizes[i] == 3840)   { iW = i; break; }
  }
  W wp;
  wp.ewih = (const float*)d_in[iW + 0];
  wp.ewhh = (const float*)d_in[iW + 1];
  wp.ebih = (const float*)d_in[iW + 2];
  wp.ebhh = (const float*)d_in[iW + 3];
  wp.dwih = (const float*)d_in[iW + 4];
  wp.dwhh = (const float*)d_in[iW + 5];
  wp.dbih = (const float*)d_in[iW + 6];
  wp.dbhh = (const float*)d_in[iW + 7];
  wp.l1w  = (const float*)d_in[iW + 8];
  wp.l1b  = (const float*)d_in[iW + 9];
  wp.l2w  = (const float*)d_in[iW + 10];
  wp.l2b  = (const float*)d_in[iW + 11];
  wp.emb  = (const float*)d_in[iW + 12];

  rnn_mfma7<<<BNTOT / 64, 256, 0, stream>>>(
      (const float*)d_in[iX], wp, (float*)d_out);
}